// Round 1
// baseline (511.203 us; speedup 1.0000x reference)
//
#include <hip/hip_runtime.h>
#include <hip/hip_bf16.h>
#include <stdint.h>
#include <stddef.h>

// Problem dims
#define Bn 128
#define Sn 1000
#define SP 1024   // padded S
#define Hn 256

typedef __bf16 bf16;
typedef __bf16 bf16x8 __attribute__((ext_vector_type(8)));
typedef __bf16 bf16x4 __attribute__((ext_vector_type(4)));
typedef __bf16 bf16x2 __attribute__((ext_vector_type(2)));
typedef float  f32x4  __attribute__((ext_vector_type(4)));

typedef __attribute__((address_space(1))) const unsigned int* gas1;
typedef __attribute__((address_space(3))) unsigned int* las3;

__device__ __forceinline__ float fast_tanh(float x){
  // 1 - 2/(e^{2x}+1): exact limits at +/-inf, no NaN for finite x
  return 1.0f - 2.0f / (__expf(2.0f * x) + 1.0f);
}
__device__ __forceinline__ float fast_sigmoid(float x){
  return 1.0f / (1.0f + __expf(-x));
}
__device__ __forceinline__ float dot4(float4 a, float4 b){
  return a.x*b.x + a.y*b.y + a.z*b.z + a.w*b.w;
}

// ---------------------------------------------------------------------------
// K0a: static fp32 -> bf16, padded to (B,1024,H); pad rows are zero.
// grid 16384 x 256; 8 elems/thread
__global__ void k0a_convert(const float* __restrict__ stat, bf16* __restrict__ Abf){
  int p = blockIdx.x * 256 + threadIdx.x;   // 4,194,304 threads
  int row = p >> 5;                         // padded row: b*1024+s
  int ch  = p & 31;                         // 8-elem chunk within H
  int s = row & (SP - 1);
  int b = row >> 10;
  float4 f0 = make_float4(0.f,0.f,0.f,0.f), f1 = f0;
  if (s < Sn){
    const float4* src = (const float4*)(stat + ((size_t)(b*Sn + s))*Hn + ch*8);
    f0 = src[0]; f1 = src[1];
  }
  bf16x8 v;
  v[0]=(bf16)f0.x; v[1]=(bf16)f0.y; v[2]=(bf16)f0.z; v[3]=(bf16)f0.w;
  v[4]=(bf16)f1.x; v[5]=(bf16)f1.y; v[6]=(bf16)f1.z; v[7]=(bf16)f1.w;
  *(bf16x8*)(Abf + (size_t)row*Hn + ch*8) = v;
}

// ---------------------------------------------------------------------------
// K0b: pack Wc (768x256 bf16, row-major, K contiguous) = [Wenc[:, :H]; Wtgt[:, :H]; Wptr[:, :H]]
// also zero score accumulators. grid 768 x 256.
__global__ void k0b_weights(const float* __restrict__ We, const float* __restrict__ Wt,
                            const float* __restrict__ Wp, bf16* __restrict__ Wcb,
                            float* __restrict__ sc_e, float* __restrict__ sc_t){
  int t = blockIdx.x * 256 + threadIdx.x;   // 196608
  if (t < Bn * SP) { sc_e[t] = 0.f; sc_t[t] = 0.f; }
  int r = t >> 8, c = t & 255;
  float val;
  if (r < 256)       val = We[r*512 + c];
  else if (r < 512)  val = Wt[(r-256)*512 + c];
  else               val = Wp[(r-512)*768 + c];
  Wcb[t] = (bf16)val;
}

// ---------------------------------------------------------------------------
// K1: GRU step + bias vectors. grid 128 (b) x 256 (h).
__global__ void k1_gru(const float* __restrict__ dec, const float* __restrict__ lhh,
                       const float* __restrict__ tgt, const float* __restrict__ se,
                       const float* __restrict__ Wih, const float* __restrict__ Whh,
                       const float* __restrict__ bih, const float* __restrict__ bhh,
                       const float* __restrict__ We,  const float* __restrict__ Wt,
                       const float* __restrict__ Wp,
                       float* __restrict__ out_hh, float* __restrict__ d_enc,
                       float* __restrict__ d_tgt,  float* __restrict__ c3){
  __shared__ __align__(16) float xs[256], hs[256], hn[256], ts[256], ss[256];
  int b = blockIdx.x, t = threadIdx.x;
  xs[t] = dec[b*256 + t];
  hs[t] = lhh[b*256 + t];
  ts[t] = tgt[b*256 + t];
  ss[t] = se[b*256 + t];
  __syncthreads();

  const float4* wir = (const float4*)(Wih + (size_t)t*256);
  const float4* wiz = (const float4*)(Wih + (size_t)(256+t)*256);
  const float4* wig = (const float4*)(Wih + (size_t)(512+t)*256);
  const float4* whr = (const float4*)(Whh + (size_t)t*256);
  const float4* whz = (const float4*)(Whh + (size_t)(256+t)*256);
  const float4* whg = (const float4*)(Whh + (size_t)(512+t)*256);
  float gir=0.f, giz=0.f, gig=0.f, ghr=0.f, ghz=0.f, ghg=0.f;
  #pragma unroll 4
  for (int k=0;k<64;k++){
    float4 xv = ((const float4*)xs)[k];
    float4 hv = ((const float4*)hs)[k];
    gir += dot4(wir[k], xv);
    giz += dot4(wiz[k], xv);
    gig += dot4(wig[k], xv);
    ghr += dot4(whr[k], hv);
    ghz += dot4(whz[k], hv);
    ghg += dot4(whg[k], hv);
  }
  gir += bih[t];      ghr += bhh[t];
  giz += bih[256+t];  ghz += bhh[256+t];
  gig += bih[512+t];  ghg += bhh[512+t];
  float r = fast_sigmoid(gir + ghr);
  float z = fast_sigmoid(giz + ghz);
  float n = fast_tanh(gig + r*ghg);
  float h = (1.f - z)*n + z*hs[t];
  hn[t] = h;
  out_hh[b*256 + t] = h;
  __syncthreads();

  const float4* we2 = (const float4*)(We + (size_t)t*512 + 256);
  const float4* wt2 = (const float4*)(Wt + (size_t)t*512 + 256);
  const float4* wp3 = (const float4*)(Wp + (size_t)t*768 + 512);
  float de=0.f, dt=0.f, cv=0.f;
  #pragma unroll 4
  for (int k=0;k<64;k++){
    float4 hv = ((const float4*)hn)[k];
    float4 tv = ((const float4*)ts)[k];
    float4 sv = ((const float4*)ss)[k];
    de += dot4(we2[k], hv);
    dt += dot4(wt2[k], tv);
    cv += dot4(wp3[k], sv);
  }
  d_enc[b*256 + t] = de;
  d_tgt[b*256 + t] = dt;
  c3[b*256 + t]    = cv;
}

// ---------------------------------------------------------------------------
// K2: fused GEMM C = Abf(128x256 tile rows) * Wc^T, m97 structure.
// grid (6 nchunk, 8 s-tile, 128 b), 256 threads (4 waves, 2x2 of 64x64).
__global__ __launch_bounds__(256) void k2_gemm(
    const bf16* __restrict__ Abf, const bf16* __restrict__ Wcb,
    const float* __restrict__ d_enc, const float* __restrict__ d_tgt,
    const float* __restrict__ c3, const float* __restrict__ v_enc,
    const float* __restrict__ v_tgt,
    float* __restrict__ sc_e, float* __restrict__ sc_t,
    bf16* __restrict__ Aptr){
  __shared__ __align__(16) bf16 As[128*64];
  __shared__ __align__(16) bf16 Bs[128*64];
  int tid = threadIdx.x;
  int w = tid >> 6, l = tid & 63;
  int nc = blockIdx.x, st = blockIdx.y, b = blockIdx.z;
  int wm = (w >> 1) * 64, wn = (w & 1) * 64;
  int lm = l & 15, q = l >> 4;

  const bf16* gA = Abf + (size_t)(b*SP + st*128) * Hn;
  const bf16* gB = Wcb + (size_t)(nc*128) * Hn;
  int srow = w*8 + (l >> 3);     // staging row (this wave, round 0)
  int scol = (l & 7) * 8;        // staging col (elems)

  f32x4 acc[4][4];
  #pragma unroll
  for (int i=0;i<4;i++)
    #pragma unroll
    for (int j=0;j<4;j++) acc[i][j] = (f32x4){0.f,0.f,0.f,0.f};

  for (int kt=0; kt<4; ++kt){
    __syncthreads();
    #pragma unroll
    for (int r=0;r<4;r++){
      int rowg = r*32 + srow;
      __builtin_amdgcn_global_load_lds((gas1)(gA + (size_t)rowg*Hn + kt*64 + scol),
                                       (las3)(&As[(r*32 + w*8)*64]), 16, 0, 0);
      __builtin_amdgcn_global_load_lds((gas1)(gB + (size_t)rowg*Hn + kt*64 + scol),
                                       (las3)(&Bs[(r*32 + w*8)*64]), 16, 0, 0);
    }
    __syncthreads();
    const bf16* Ab = &As[(wm + lm)*64 + q*8];
    const bf16* Bb = &Bs[(wn + lm)*64 + q*8];
    #pragma unroll
    for (int kk=0; kk<64; kk+=32){
      bf16x8 af[4], bfr[4];
      #pragma unroll
      for (int i=0;i<4;i++) af[i]  = *(const bf16x8*)(Ab + i*16*64 + kk);
      #pragma unroll
      for (int j=0;j<4;j++) bfr[j] = *(const bf16x8*)(Bb + j*16*64 + kk);
      #pragma unroll
      for (int i=0;i<4;i++)
        #pragma unroll
        for (int j=0;j<4;j++)
          acc[i][j] = __builtin_amdgcn_mfma_f32_16x16x32_bf16(af[i], bfr[j], acc[i][j], 0, 0, 0);
    }
  }

  int hb = (nc & 1) * 128;   // h offset within the 256-col group
  if (nc < 4){
    // score chunks: partial[m] = sum_h v[h]*tanh(C[m,h]+d[b,h]) -> atomicAdd
    const float* vv = (nc < 2) ? v_enc : v_tgt;
    const float* db = ((nc < 2) ? d_enc : d_tgt) + b*256;
    float* sc = ((nc < 2) ? sc_e : sc_t) + b*SP + st*128;
    float vj[4], dj[4];
    #pragma unroll
    for (int j=0;j<4;j++){
      int hh = hb + wn + j*16 + lm;
      vj[j] = vv[hh]; dj[j] = db[hh];
    }
    #pragma unroll
    for (int i=0;i<4;i++){
      #pragma unroll
      for (int r=0;r<4;r++){
        float p = 0.f;
        #pragma unroll
        for (int j=0;j<4;j++) p += vj[j] * fast_tanh(acc[i][j][r] + dj[j]);
        p += __shfl_xor(p, 1);
        p += __shfl_xor(p, 2);
        p += __shfl_xor(p, 4);
        p += __shfl_xor(p, 8);
        if (lm == 0) atomicAdd(&sc[wm + i*16 + q*4 + r], p);
      }
    }
  } else {
    // pointer chunks: Aptr[m,h] = C[m,h] + c3[b,h]  (bf16, pre-tanh)
    const float* c3b = c3 + b*256;
    size_t rbase = (size_t)(b*SP + st*128);
    #pragma unroll
    for (int j=0;j<4;j++){
      int hh = hb + wn + j*16 + lm;
      float cv = c3b[hh];
      #pragma unroll
      for (int i=0;i<4;i++){
        #pragma unroll
        for (int r=0;r<4;r++){
          int row = wm + i*16 + q*4 + r;
          Aptr[(rbase + row)*Hn + hh] = (bf16)(acc[i][j][r] + cv);
        }
      }
    }
  }
}

// ---------------------------------------------------------------------------
// K3: softmax over s + context + c2 = Wptr[:,H:2H] @ context. grid (128 b, 2 which) x 256.
__global__ void k3_softmax_ctx(const float* __restrict__ sc_e, const float* __restrict__ sc_t,
                               const bf16* __restrict__ Abf, const float* __restrict__ Wp,
                               float* __restrict__ c2e, float* __restrict__ c2t){
  int b = blockIdx.x, which = blockIdx.y, t = threadIdx.x;
  const float* sc = which ? sc_t : sc_e;
  float* c2 = which ? c2t : c2e;
  __shared__ __align__(16) float at[Sn];
  __shared__ float red[256];
  __shared__ __align__(16) float ctx[256];
  __shared__ float2 partc[2][128];

  float lmax = -1e30f;
  #pragma unroll
  for (int i=0;i<4;i++){
    int s = t + i*256;
    if (s < Sn){ float v = sc[b*SP + s]; at[s] = v; lmax = fmaxf(lmax, v); }
  }
  red[t] = lmax; __syncthreads();
  for (int o=128;o>0;o>>=1){ if (t < o) red[t] = fmaxf(red[t], red[t+o]); __syncthreads(); }
  float mx = red[0]; __syncthreads();

  float lsum = 0.f;
  #pragma unroll
  for (int i=0;i<4;i++){
    int s = t + i*256;
    if (s < Sn){ float e = __expf(at[s] - mx); at[s] = e; lsum += e; }
  }
  red[t] = lsum; __syncthreads();
  for (int o=128;o>0;o>>=1){ if (t < o) red[t] += red[t+o]; __syncthreads(); }
  float inv = 1.0f / red[0];
  #pragma unroll
  for (int i=0;i<4;i++){
    int s = t + i*256;
    if (s < Sn) at[s] *= inv;
  }
  __syncthreads();

  // context: thread handles 2 h over half the s range
  int hp = t & 127, sh = t >> 7;
  float a0 = 0.f, a1 = 0.f;
  const bf16* base = Abf + ((size_t)(b*SP + sh*500))*Hn + hp*2;
  #pragma unroll 4
  for (int s2=0; s2<500; s2++){
    float wgt = at[sh*500 + s2];
    bf16x2 pr = *(const bf16x2*)(base + (size_t)s2*Hn);
    a0 += wgt * (float)pr[0];
    a1 += wgt * (float)pr[1];
  }
  partc[sh][hp] = make_float2(a0, a1);
  __syncthreads();
  if (t < 128){
    float2 p0 = partc[0][t], p1 = partc[1][t];
    ctx[2*t]   = p0.x + p1.x;
    ctx[2*t+1] = p0.y + p1.y;
  }
  __syncthreads();

  const float4* wrow = (const float4*)(Wp + (size_t)t*768 + 256);
  float acc = 0.f;
  #pragma unroll 4
  for (int k=0;k<64;k++) acc += dot4(wrow[k], ((const float4*)ctx)[k]);
  c2[b*256 + t] = acc;
}

// ---------------------------------------------------------------------------
// K4: out[m] = 5*sum_h vp[h]*tanh(Aptr[m,h]+c2e[b,h]) + sum_h vp[h]*tanh(Aptr[m,h]+c2t[b,h])
// one wave per row. grid 32000 x 256.
__global__ void k4_final(const bf16* __restrict__ Aptr, const float* __restrict__ c2e,
                         const float* __restrict__ c2t, const float* __restrict__ vp,
                         float* __restrict__ out){
  int w = threadIdx.x >> 6, l = threadIdx.x & 63;
  int row = blockIdx.x*4 + w;              // 0..127999 == b*1000+s
  int b = row / 1000;
  int s = row - b*1000;
  const bf16* ap = Aptr + ((size_t)(b*SP + s))*Hn + l*4;
  bf16x4 av = *(const bf16x4*)ap;
  float4 ce = *(const float4*)(c2e + b*256 + l*4);
  float4 ct = *(const float4*)(c2t + b*256 + l*4);
  float4 vv = *(const float4*)(vp + l*4);
  float a0 = (float)av[0], a1 = (float)av[1], a2 = (float)av[2], a3 = (float)av[3];
  float pe = vv.x*fast_tanh(a0+ce.x) + vv.y*fast_tanh(a1+ce.y)
           + vv.z*fast_tanh(a2+ce.z) + vv.w*fast_tanh(a3+ce.w);
  float pt = vv.x*fast_tanh(a0+ct.x) + vv.y*fast_tanh(a1+ct.y)
           + vv.z*fast_tanh(a2+ct.z) + vv.w*fast_tanh(a3+ct.w);
  #pragma unroll
  for (int o=1;o<64;o<<=1){
    pe += __shfl_xor(pe, o);
    pt += __shfl_xor(pt, o);
  }
  if (l == 0) out[row] = 5.0f*pe + pt;
}

// ---------------------------------------------------------------------------
extern "C" void kernel_launch(void* const* d_in, const int* in_sizes, int n_in,
                              void* d_out, int out_size, void* d_ws, size_t ws_size,
                              hipStream_t stream){
  const float* stat = (const float*)d_in[0];
  const float* se   = (const float*)d_in[1];
  const float* dec  = (const float*)d_in[2];
  const float* tgt  = (const float*)d_in[3];
  const float* lhh  = (const float*)d_in[4];
  const float* Wih  = (const float*)d_in[5];
  const float* Whh  = (const float*)d_in[6];
  const float* bih  = (const float*)d_in[7];
  const float* bhh  = (const float*)d_in[8];
  const float* vEnc = (const float*)d_in[9];
  const float* WEnc = (const float*)d_in[10];
  const float* vTgt = (const float*)d_in[11];
  const float* WTgt = (const float*)d_in[12];
  const float* vPtr = (const float*)d_in[13];
  const float* WPtr = (const float*)d_in[14];
  float* out = (float*)d_out;

  char* wsp = (char*)d_ws;
  // layout (bytes):
  bf16*  Abf  = (bf16*)(wsp);                    // 128*1024*256*2 = 67108864
  bf16*  Aptr = (bf16*)(wsp + 67108864);         // 67108864
  bf16*  Wcb  = (bf16*)(wsp + 134217728);        // 393216
  float* scE  = (float*)(wsp + 134610944);       // 524288
  float* scT  = (float*)(wsp + 135135232);       // 524288
  float* dEnc = (float*)(wsp + 135659520);       // 131072
  float* dTgt = (float*)(wsp + 135790592);       // 131072
  float* c3   = (float*)(wsp + 135921664);       // 131072
  float* c2e  = (float*)(wsp + 136052736);       // 131072
  float* c2t  = (float*)(wsp + 136183808);       // 131072 -> total 136314880+131072

  hipLaunchKernelGGL(k0a_convert, dim3(16384), dim3(256), 0, stream, stat, Abf);
  hipLaunchKernelGGL(k0b_weights, dim3(768), dim3(256), 0, stream,
                     WEnc, WTgt, WPtr, Wcb, scE, scT);
  hipLaunchKernelGGL(k1_gru, dim3(128), dim3(256), 0, stream,
                     dec, lhh, tgt, se, Wih, Whh, bih, bhh, WEnc, WTgt, WPtr,
                     out + Bn*Sn, dEnc, dTgt, c3);
  hipLaunchKernelGGL(k2_gemm, dim3(6, 8, 128), dim3(256), 0, stream,
                     Abf, Wcb, dEnc, dTgt, c3, vEnc, vTgt, scE, scT, Aptr);
  hipLaunchKernelGGL(k3_softmax_ctx, dim3(128, 2), dim3(256), 0, stream,
                     scE, scT, Abf, WPtr, c2e, c2t);
  hipLaunchKernelGGL(k4_final, dim3(32000), dim3(256), 0, stream,
                     Aptr, c2e, c2t, vPtr, out);
}

// Round 2
// 464.097 us; speedup vs baseline: 1.1015x; 1.1015x over previous
//
#include <hip/hip_runtime.h>
#include <hip/hip_bf16.h>
#include <stdint.h>
#include <stddef.h>

// Problem dims
#define Bn 128
#define Sn 1000
#define SP 1024   // padded S
#define Hn 256

typedef __bf16 bf16;
typedef __bf16 bf16x8 __attribute__((ext_vector_type(8)));
typedef __bf16 bf16x4 __attribute__((ext_vector_type(4)));
typedef __bf16 bf16x2 __attribute__((ext_vector_type(2)));
typedef float  f32x4  __attribute__((ext_vector_type(4)));

typedef __attribute__((address_space(1))) const unsigned int* gas1;
typedef __attribute__((address_space(3))) unsigned int* las3;

__device__ __forceinline__ float fast_tanh(float x){
  return 1.0f - 2.0f / (__expf(2.0f * x) + 1.0f);
}
__device__ __forceinline__ float fast_sigmoid(float x){
  return 1.0f / (1.0f + __expf(-x));
}
__device__ __forceinline__ float dot4(float4 a, float4 b){
  return a.x*b.x + a.y*b.y + a.z*b.z + a.w*b.w;
}

// ---------------------------------------------------------------------------
// K0a: static fp32 -> bf16, padded to (B,1024,H); pad rows are zero.
__global__ void k0a_convert(const float* __restrict__ stat, bf16* __restrict__ Abf){
  int p = blockIdx.x * 256 + threadIdx.x;   // 4,194,304 threads
  int row = p >> 5;                         // padded row: b*1024+s
  int ch  = p & 31;                         // 8-elem chunk within H
  int s = row & (SP - 1);
  int b = row >> 10;
  float4 f0 = make_float4(0.f,0.f,0.f,0.f), f1 = f0;
  if (s < Sn){
    const float4* src = (const float4*)(stat + ((size_t)(b*Sn + s))*Hn + ch*8);
    f0 = src[0]; f1 = src[1];
  }
  bf16x8 v;
  v[0]=(bf16)f0.x; v[1]=(bf16)f0.y; v[2]=(bf16)f0.z; v[3]=(bf16)f0.w;
  v[4]=(bf16)f1.x; v[5]=(bf16)f1.y; v[6]=(bf16)f1.z; v[7]=(bf16)f1.w;
  *(bf16x8*)(Abf + (size_t)row*Hn + ch*8) = v;
}

// ---------------------------------------------------------------------------
// K0b: pack Wc (768x256 bf16, row-major, K contiguous)
__global__ void k0b_weights(const float* __restrict__ We, const float* __restrict__ Wt,
                            const float* __restrict__ Wp, bf16* __restrict__ Wcb){
  int t = blockIdx.x * 256 + threadIdx.x;   // 196608
  int r = t >> 8, c = t & 255;
  float val;
  if (r < 256)       val = We[r*512 + c];
  else if (r < 512)  val = Wt[(r-256)*512 + c];
  else               val = Wp[(r-512)*768 + c];
  Wcb[t] = (bf16)val;
}

// ---------------------------------------------------------------------------
// K1: GRU step + bias vectors. grid 128 (b) x 256 (h).
__global__ void k1_gru(const float* __restrict__ dec, const float* __restrict__ lhh,
                       const float* __restrict__ tgt, const float* __restrict__ se,
                       const float* __restrict__ Wih, const float* __restrict__ Whh,
                       const float* __restrict__ bih, const float* __restrict__ bhh,
                       const float* __restrict__ We,  const float* __restrict__ Wt,
                       const float* __restrict__ Wp,
                       float* __restrict__ out_hh, float* __restrict__ d_enc,
                       float* __restrict__ d_tgt,  float* __restrict__ c3){
  __shared__ __align__(16) float xs[256], hs[256], hn[256], ts[256], ss[256];
  int b = blockIdx.x, t = threadIdx.x;
  xs[t] = dec[b*256 + t];
  hs[t] = lhh[b*256 + t];
  ts[t] = tgt[b*256 + t];
  ss[t] = se[b*256 + t];
  __syncthreads();

  const float4* wir = (const float4*)(Wih + (size_t)t*256);
  const float4* wiz = (const float4*)(Wih + (size_t)(256+t)*256);
  const float4* wig = (const float4*)(Wih + (size_t)(512+t)*256);
  const float4* whr = (const float4*)(Whh + (size_t)t*256);
  const float4* whz = (const float4*)(Whh + (size_t)(256+t)*256);
  const float4* whg = (const float4*)(Whh + (size_t)(512+t)*256);
  float gir=0.f, giz=0.f, gig=0.f, ghr=0.f, ghz=0.f, ghg=0.f;
  #pragma unroll 4
  for (int k=0;k<64;k++){
    float4 xv = ((const float4*)xs)[k];
    float4 hv = ((const float4*)hs)[k];
    gir += dot4(wir[k], xv);
    giz += dot4(wiz[k], xv);
    gig += dot4(wig[k], xv);
    ghr += dot4(whr[k], hv);
    ghz += dot4(whz[k], hv);
    ghg += dot4(whg[k], hv);
  }
  gir += bih[t];      ghr += bhh[t];
  giz += bih[256+t];  ghz += bhh[256+t];
  gig += bih[512+t];  ghg += bhh[512+t];
  float r = fast_sigmoid(gir + ghr);
  float z = fast_sigmoid(giz + ghz);
  float n = fast_tanh(gig + r*ghg);
  float h = (1.f - z)*n + z*hs[t];
  hn[t] = h;
  out_hh[b*256 + t] = h;
  __syncthreads();

  const float4* we2 = (const float4*)(We + (size_t)t*512 + 256);
  const float4* wt2 = (const float4*)(Wt + (size_t)t*512 + 256);
  const float4* wp3 = (const float4*)(Wp + (size_t)t*768 + 512);
  float de=0.f, dt=0.f, cv=0.f;
  #pragma unroll 4
  for (int k=0;k<64;k++){
    float4 hv = ((const float4*)hn)[k];
    float4 tv = ((const float4*)ts)[k];
    float4 sv = ((const float4*)ss)[k];
    de += dot4(we2[k], hv);
    dt += dot4(wt2[k], tv);
    cv += dot4(wp3[k], sv);
  }
  d_enc[b*256 + t] = de;
  d_tgt[b*256 + t] = dt;
  c3[b*256 + t]    = cv;
}

// ---------------------------------------------------------------------------
// K2: fused GEMM. One block owns an M=64 A-tile (staged once, swizzled),
// loops 6 N-chunks (enc/enc/tgt/tgt/ptr/ptr) re-staging only B (L2-hot).
// grid (16 st, 128 b), 256 threads = 4 waves, each wave 32(M) x 64(N).
// LDS chunk swizzle: 16B chunk c of row r stored at chunk c^(r&7) -> conflict-free ds_read_b128.
__global__ __launch_bounds__(256) void k2_gemm(
    const bf16* __restrict__ Abf, const bf16* __restrict__ Wcb,
    const float* __restrict__ d_enc, const float* __restrict__ d_tgt,
    const float* __restrict__ c3, const float* __restrict__ v_enc,
    const float* __restrict__ v_tgt,
    float* __restrict__ sc_e, float* __restrict__ sc_t,
    bf16* __restrict__ Aptr){
  __shared__ __align__(16) bf16 As[64*256];    // 32 KB
  __shared__ __align__(16) bf16 Bs[128*64];    // 16 KB
  __shared__ float scoreE[64], scoreT[64];
  int tid = threadIdx.x;
  int w = tid >> 6, l = tid & 63;
  int st = blockIdx.x, b = blockIdx.y;
  int wm = (w & 1) * 32, wn = (w >> 1) * 64;
  int lm = l & 15, q = l >> 4;

  if (tid < 64) scoreE[tid] = 0.f;
  else if (tid < 128) scoreT[tid-64] = 0.f;

  // stage A once: 64 rows x 256 K (swizzled). 8 issues x (4 waves x 2 rows).
  {
    const bf16* gA = Abf + ((size_t)(b*SP + st*64)) * Hn;
    int rl = w*2 + (l >> 5);
    int ch = l & 31;
    #pragma unroll
    for (int is = 0; is < 8; is++){
      int row = is*8 + rl;
      int sc_ = ch ^ (row & 7);
      __builtin_amdgcn_global_load_lds((gas1)(gA + (size_t)row*256 + sc_*8),
                                       (las3)(&As[(is*8 + w*2)*256]), 16, 0, 0);
    }
  }

  int rB8 = w*8 + (l >> 3);
  int chB = l & 7;

  for (int nc = 0; nc < 6; nc++){
    f32x4 acc[2][4];
    #pragma unroll
    for (int i=0;i<2;i++)
      #pragma unroll
      for (int j=0;j<4;j++) acc[i][j] = (f32x4){0.f,0.f,0.f,0.f};

    for (int kt = 0; kt < 4; kt++){
      __syncthreads();   // prior compute done (and A-stage drained on first pass)
      #pragma unroll
      for (int is = 0; is < 4; is++){
        int row = is*32 + rB8;
        int sc_ = chB ^ (row & 7);
        __builtin_amdgcn_global_load_lds((gas1)(Wcb + ((size_t)(nc*128 + row))*256 + kt*64 + sc_*8),
                                         (las3)(&Bs[(is*32 + w*8)*64]), 16, 0, 0);
      }
      __syncthreads();   // B staged
      #pragma unroll
      for (int kk = 0; kk < 64; kk += 32){
        bf16x8 af[2], bfr[4];
        int cA = kt*8 + (kk >> 3) + q;    // 0..31
        int cB = (kk >> 3) + q;           // 0..7
        #pragma unroll
        for (int i=0;i<2;i++){
          int rA = wm + i*16 + lm;
          af[i] = *(const bf16x8*)(&As[rA*256 + ((cA ^ (rA & 7)) << 3)]);
        }
        #pragma unroll
        for (int j=0;j<4;j++){
          int rB = wn + j*16 + lm;
          bfr[j] = *(const bf16x8*)(&Bs[rB*64 + ((cB ^ (rB & 7)) << 3)]);
        }
        #pragma unroll
        for (int i=0;i<2;i++)
          #pragma unroll
          for (int j=0;j<4;j++)
            acc[i][j] = __builtin_amdgcn_mfma_f32_16x16x32_bf16(af[i], bfr[j], acc[i][j], 0, 0, 0);
      }
    }

    // epilogue for this N-chunk
    int hb = (nc & 1) * 128;
    if (nc < 4){
      const float* vv = (nc < 2) ? v_enc : v_tgt;
      const float* db = ((nc < 2) ? d_enc : d_tgt) + b*256;
      float* sc = (nc < 2) ? scoreE : scoreT;
      float vj[4], dj[4];
      #pragma unroll
      for (int j=0;j<4;j++){
        int hh = hb + wn + j*16 + lm;
        vj[j] = vv[hh]; dj[j] = db[hh];
      }
      #pragma unroll
      for (int i=0;i<2;i++){
        #pragma unroll
        for (int r=0;r<4;r++){
          float p = 0.f;
          #pragma unroll
          for (int j=0;j<4;j++) p += vj[j] * fast_tanh(acc[i][j][r] + dj[j]);
          p += __shfl_xor(p, 1);
          p += __shfl_xor(p, 2);
          p += __shfl_xor(p, 4);
          p += __shfl_xor(p, 8);
          if (lm == 0) atomicAdd(&sc[wm + i*16 + q*4 + r], p);
        }
      }
    } else {
      int hbp = (nc - 4) * 128;
      const float* c3b = c3 + b*256;
      float cv[4]; int hhj[4];
      #pragma unroll
      for (int j=0;j<4;j++){
        hhj[j] = hbp + wn + j*16 + lm;
        cv[j] = c3b[hhj[j]];
      }
      #pragma unroll
      for (int i=0;i<2;i++){
        #pragma unroll
        for (int r=0;r<4;r++){
          int row = wm + i*16 + q*4 + r;
          int gs = st*64 + row;
          if (gs < Sn){
            size_t rb = ((size_t)(b*Sn + gs))*256;
            #pragma unroll
            for (int j=0;j<4;j++)
              Aptr[rb + hhj[j]] = (bf16)(acc[i][j][r] + cv[j]);
          }
        }
      }
    }
  }

  __syncthreads();
  if (tid < 64)       sc_e[b*SP + st*64 + tid]      = scoreE[tid];
  else if (tid < 128) sc_t[b*SP + st*64 + tid - 64] = scoreT[tid-64];
}

// ---------------------------------------------------------------------------
// K3b: per (b, s-split): softmax over full S for BOTH branches, then context
// partials for both branches from ONE pass over A. grid (128, 2) x 1024.
__global__ __launch_bounds__(1024) void k3_ctx(
    const float* __restrict__ sc_e, const float* __restrict__ sc_t,
    const bf16* __restrict__ Abf,
    float* __restrict__ ctxPE, float* __restrict__ ctxPT){
  __shared__ float attE[1024], attT[1024];
  __shared__ float redE[16], redT[16];
  __shared__ float pe[8*256], pt[8*256];
  int b = blockIdx.x, sp = blockIdx.y, t = threadIdx.x;
  int wid = t >> 6, ln = t & 63;

  float vE = (t < Sn) ? sc_e[b*SP + t] : -1e30f;
  float vT = (t < Sn) ? sc_t[b*SP + t] : -1e30f;
  float mE = vE, mT = vT;
  #pragma unroll
  for (int o=1;o<64;o<<=1){ mE = fmaxf(mE, __shfl_xor(mE,o)); mT = fmaxf(mT, __shfl_xor(mT,o)); }
  if (ln == 0){ redE[wid] = mE; redT[wid] = mT; }
  __syncthreads();
  float ME = -1e30f, MT = -1e30f;
  #pragma unroll
  for (int i=0;i<16;i++){ ME = fmaxf(ME, redE[i]); MT = fmaxf(MT, redT[i]); }
  __syncthreads();
  float eE = (t < Sn) ? __expf(vE - ME) : 0.f;
  float eT = (t < Sn) ? __expf(vT - MT) : 0.f;
  float sE = eE, sT = eT;
  #pragma unroll
  for (int o=1;o<64;o<<=1){ sE += __shfl_xor(sE,o); sT += __shfl_xor(sT,o); }
  if (ln == 0){ redE[wid] = sE; redT[wid] = sT; }
  __syncthreads();
  float SE = 0.f, ST = 0.f;
  #pragma unroll
  for (int i=0;i<16;i++){ SE += redE[i]; ST += redT[i]; }
  attE[t] = eE / SE;
  attT[t] = eT / ST;
  __syncthreads();

  // context over this split's 500 rows, both branches, one A pass.
  int sh = t >> 7, hp = t & 127;
  const bf16* base = Abf + ((size_t)(b*SP + sp*500))*Hn + hp*2;
  float aE0=0.f, aE1=0.f, aT0=0.f, aT1=0.f;
  #pragma unroll 4
  for (int i=0;i<63;i++){
    int sl = sh + 8*i;
    if (sl < 500){
      int s = sp*500 + sl;
      float wE = attE[s], wT = attT[s];
      bf16x2 pr = *(const bf16x2*)(base + (size_t)sl*Hn);
      float p0 = (float)pr[0], p1 = (float)pr[1];
      aE0 += wE*p0; aE1 += wE*p1;
      aT0 += wT*p0; aT1 += wT*p1;
    }
  }
  pe[sh*256 + hp*2] = aE0; pe[sh*256 + hp*2+1] = aE1;
  pt[sh*256 + hp*2] = aT0; pt[sh*256 + hp*2+1] = aT1;
  __syncthreads();
  if (t < 256){
    float s = 0.f;
    #pragma unroll
    for (int i=0;i<8;i++) s += pe[i*256 + t];
    ctxPE[((size_t)(sp*Bn + b))*256 + t] = s;
  } else if (t < 512){
    int tt = t - 256;
    float s = 0.f;
    #pragma unroll
    for (int i=0;i<8;i++) s += pt[i*256 + tt];
    ctxPT[((size_t)(sp*Bn + b))*256 + tt] = s;
  }
}

// ---------------------------------------------------------------------------
// K3c: c2 = Wptr[:,H:2H] @ (ctx_part0 + ctx_part1). grid (128, 2) x 256.
__global__ void k3c_c2(const float* __restrict__ ctxPE, const float* __restrict__ ctxPT,
                       const float* __restrict__ Wp,
                       float* __restrict__ c2e, float* __restrict__ c2t){
  __shared__ __align__(16) float ctx[256];
  int b = blockIdx.x, which = blockIdx.y, t = threadIdx.x;
  const float* cp = which ? ctxPT : ctxPE;
  ctx[t] = cp[(size_t)b*256 + t] + cp[((size_t)(Bn + b))*256 + t];
  __syncthreads();
  const float4* wrow = (const float4*)(Wp + (size_t)t*768 + 256);
  float acc = 0.f;
  #pragma unroll 4
  for (int k=0;k<64;k++) acc += dot4(wrow[k], ((const float4*)ctx)[k]);
  (which ? c2t : c2e)[b*256 + t] = acc;
}

// ---------------------------------------------------------------------------
// K4: out[m] = 5*sum_h vp[h]*tanh(Aptr[m,h]+c2e[b,h]) + sum_h vp[h]*tanh(Aptr[m,h]+c2t[b,h])
__global__ void k4_final(const bf16* __restrict__ Aptr, const float* __restrict__ c2e,
                         const float* __restrict__ c2t, const float* __restrict__ vp,
                         float* __restrict__ out){
  int w = threadIdx.x >> 6, l = threadIdx.x & 63;
  int row = blockIdx.x*4 + w;              // 0..127999 == b*1000+s
  int b = row / 1000;
  const bf16* ap = Aptr + (size_t)row*Hn + l*4;
  bf16x4 av = *(const bf16x4*)ap;
  float4 ce = *(const float4*)(c2e + b*256 + l*4);
  float4 ct = *(const float4*)(c2t + b*256 + l*4);
  float4 vv = *(const float4*)(vp + l*4);
  float a0 = (float)av[0], a1 = (float)av[1], a2 = (float)av[2], a3 = (float)av[3];
  float pe = vv.x*fast_tanh(a0+ce.x) + vv.y*fast_tanh(a1+ce.y)
           + vv.z*fast_tanh(a2+ce.z) + vv.w*fast_tanh(a3+ce.w);
  float pt = vv.x*fast_tanh(a0+ct.x) + vv.y*fast_tanh(a1+ct.y)
           + vv.z*fast_tanh(a2+ct.z) + vv.w*fast_tanh(a3+ct.w);
  #pragma unroll
  for (int o=1;o<64;o<<=1){
    pe += __shfl_xor(pe, o);
    pt += __shfl_xor(pt, o);
  }
  if (l == 0) out[row] = 5.0f*pe + pt;
}

// ---------------------------------------------------------------------------
extern "C" void kernel_launch(void* const* d_in, const int* in_sizes, int n_in,
                              void* d_out, int out_size, void* d_ws, size_t ws_size,
                              hipStream_t stream){
  const float* stat = (const float*)d_in[0];
  const float* se   = (const float*)d_in[1];
  const float* dec  = (const float*)d_in[2];
  const float* tgt  = (const float*)d_in[3];
  const float* lhh  = (const float*)d_in[4];
  const float* Wih  = (const float*)d_in[5];
  const float* Whh  = (const float*)d_in[6];
  const float* bih  = (const float*)d_in[7];
  const float* bhh  = (const float*)d_in[8];
  const float* vEnc = (const float*)d_in[9];
  const float* WEnc = (const float*)d_in[10];
  const float* vTgt = (const float*)d_in[11];
  const float* WTgt = (const float*)d_in[12];
  const float* vPtr = (const float*)d_in[13];
  const float* WPtr = (const float*)d_in[14];
  float* out = (float*)d_out;

  char* wsp = (char*)d_ws;
  bf16*  Abf  = (bf16*)(wsp);                    // 67,108,864
  bf16*  Aptr = (bf16*)(wsp + 67108864);         // 65,536,000 (compact: 128*1000*256*2)
  bf16*  Wcb  = (bf16*)(wsp + 132644864);        // 393,216
  float* scE  = (float*)(wsp + 133038080);       // 524,288
  float* scT  = (float*)(wsp + 133562368);       // 524,288
  float* dEnc = (float*)(wsp + 134086656);       // 131,072
  float* dTgt = (float*)(wsp + 134217728);       // 131,072
  float* c3   = (float*)(wsp + 134348800);       // 131,072
  float* c2e  = (float*)(wsp + 134479872);       // 131,072
  float* c2t  = (float*)(wsp + 134610944);       // 131,072
  float* ctxPE= (float*)(wsp + 134742016);       // 262,144
  float* ctxPT= (float*)(wsp + 135004160);       // 262,144 -> end 135,266,304

  hipLaunchKernelGGL(k0a_convert, dim3(16384), dim3(256), 0, stream, stat, Abf);
  hipLaunchKernelGGL(k0b_weights, dim3(768), dim3(256), 0, stream, WEnc, WTgt, WPtr, Wcb);
  hipLaunchKernelGGL(k1_gru, dim3(128), dim3(256), 0, stream,
                     dec, lhh, tgt, se, Wih, Whh, bih, bhh, WEnc, WTgt, WPtr,
                     out + Bn*Sn, dEnc, dTgt, c3);
  hipLaunchKernelGGL(k2_gemm, dim3(16, 128), dim3(256), 0, stream,
                     Abf, Wcb, dEnc, dTgt, c3, vEnc, vTgt, scE, scT, Aptr);
  hipLaunchKernelGGL(k3_ctx, dim3(128, 2), dim3(1024), 0, stream,
                     scE, scT, Abf, ctxPE, ctxPT);
  hipLaunchKernelGGL(k3c_c2, dim3(128, 2), dim3(256), 0, stream,
                     ctxPE, ctxPT, WPtr, c2e, c2t);
  hipLaunchKernelGGL(k4_final, dim3(32000), dim3(256), 0, stream,
                     Aptr, c2e, c2t, vPtr, out);
}